// Round 1
// baseline (377.470 us; speedup 1.0000x reference)
//
#include <hip/hip_runtime.h>
#include <math.h>

#define MIN_NORM 1e-15f
#define BALL_EPS 0.004f

constexpr int D  = 256;
constexpr int NQ = 200000;
constexpr float SCALE = 0.0625f;   // 1/sqrt(256)

__device__ __forceinline__ float wave_sum(float v) {
    #pragma unroll
    for (int off = 32; off > 0; off >>= 1) v += __shfl_xor(v, off, 64);
    return v;
}

__global__ __launch_bounds__(256) void atth_kernel(
    const int*   __restrict__ queries,
    const float* __restrict__ entity_emb,
    const float* __restrict__ rel_emb,
    const float* __restrict__ bias_head,
    const float* __restrict__ bias_tail,
    const float* __restrict__ c_arr,
    const float* __restrict__ att_rel_emb,
    const float* __restrict__ context_emb,
    float*       __restrict__ out)
{
    const int wave = threadIdx.x >> 6;
    const int lane = threadIdx.x & 63;
    const int q = blockIdx.x * 4 + wave;
    if (q >= NQ) return;

    const int h = queries[q * 3 + 0];
    const int r = queries[q * 3 + 1];
    const int t = queries[q * 3 + 2];

    // c_q = softplus(c[r])
    const float craw = c_arr[r];
    const float c = (craw > 20.0f) ? craw : log1pf(expf(craw));
    const float sqrt_c = sqrtf(c);

    const int e4 = lane * 4;

    const float4 head = *(const float4*)(entity_emb  + (size_t)h * D       + e4);
    const float4 tail = *(const float4*)(entity_emb  + (size_t)t * D       + e4);
    const float4 rel0 = *(const float4*)(rel_emb     + (size_t)r * 2 * D       + e4);
    const float4 rel1 = *(const float4*)(rel_emb     + (size_t)r * 2 * D + D   + e4);
    const float4 rotm = *(const float4*)(att_rel_emb + (size_t)r * 2 * D       + e4);
    const float4 refm = *(const float4*)(att_rel_emb + (size_t)r * 2 * D + D   + e4);
    const float4 ctx  = *(const float4*)(context_emb + (size_t)r * D       + e4);

    const float hd[4]  = {head.x, head.y, head.z, head.w};
    const float tl[4]  = {tail.x, tail.y, tail.z, tail.w};
    const float rm[4]  = {rotm.x, rotm.y, rotm.z, rotm.w};
    const float fm[4]  = {refm.x, refm.y, refm.z, refm.w};
    const float cx[4]  = {ctx.x,  ctx.y,  ctx.z,  ctx.w};
    const float rl[4]  = {rel0.x, rel0.y, rel0.z, rel0.w};

    // Givens rotation (rot_mat) and reflection (ref_mat) on the 2 local pairs
    float rq[4], fq[4];
    #pragma unroll
    for (int p = 0; p < 2; ++p) {
        const int i0 = 2 * p, i1 = 2 * p + 1;
        // rotation
        float g0 = rm[i0], g1 = rm[i1];
        float n  = fmaxf(sqrtf(g0 * g0 + g1 * g1), MIN_NORM);
        g0 /= n; g1 /= n;
        rq[i0] = g0 * hd[i0] - g1 * hd[i1];
        rq[i1] = g0 * hd[i1] + g1 * hd[i0];
        // reflection
        float e0 = fm[i0], e1 = fm[i1];
        float m  = fmaxf(sqrtf(e0 * e0 + e1 * e1), MIN_NORM);
        e0 /= m; e1 /= m;
        fq[i0] = e0 * hd[i0] + e1 * hd[i1];
        fq[i1] = e1 * hd[i0] - e0 * hd[i1];
    }

    // attention over {ref_q, rot_q}
    float sref = 0.0f, srot = 0.0f;
    #pragma unroll
    for (int j = 0; j < 4; ++j) { sref += cx[j] * fq[j]; srot += cx[j] * rq[j]; }
    sref = wave_sum(sref) * SCALE;
    srot = wave_sum(srot) * SCALE;
    const float mx = fmaxf(sref, srot);
    const float eref = expf(sref - mx), erot = expf(srot - mx);
    const float inv_se = 1.0f / (eref + erot);
    const float wref = eref * inv_se, wrot = erot * inv_se;

    float att[4];
    #pragma unroll
    for (int j = 0; j < 4; ++j) att[j] = wref * fq[j] + wrot * rq[j];

    const float maxnorm = (1.0f - BALL_EPS) / sqrt_c;

    // lhs = expmap0(att_q, c) with project
    float s = 0.0f;
    #pragma unroll
    for (int j = 0; j < 4; ++j) s += att[j] * att[j];
    float un = fmaxf(sqrtf(wave_sum(s)), MIN_NORM);
    float fac = tanhf(sqrt_c * un) / (sqrt_c * un);
    float lhs[4];
    #pragma unroll
    for (int j = 0; j < 4; ++j) lhs[j] = fac * att[j];
    s = 0.0f;
    #pragma unroll
    for (int j = 0; j < 4; ++j) s += lhs[j] * lhs[j];
    float nrm = fmaxf(sqrtf(wave_sum(s)), MIN_NORM);
    if (nrm > maxnorm) {
        const float sc = maxnorm / nrm;
        #pragma unroll
        for (int j = 0; j < 4; ++j) lhs[j] *= sc;
    }

    // rel = expmap0(rel_emb[r][:D], c) with project
    s = 0.0f;
    #pragma unroll
    for (int j = 0; j < 4; ++j) s += rl[j] * rl[j];
    un = fmaxf(sqrtf(wave_sum(s)), MIN_NORM);
    fac = tanhf(sqrt_c * un) / (sqrt_c * un);
    float rh[4];
    #pragma unroll
    for (int j = 0; j < 4; ++j) rh[j] = fac * rl[j];
    s = 0.0f;
    #pragma unroll
    for (int j = 0; j < 4; ++j) s += rh[j] * rh[j];
    nrm = fmaxf(sqrtf(wave_sum(s)), MIN_NORM);
    if (nrm > maxnorm) {
        const float sc = maxnorm / nrm;
        #pragma unroll
        for (int j = 0; j < 4; ++j) rh[j] *= sc;
    }

    // mobius_add(lhs, rh, c)
    float sx = 0.0f, sy = 0.0f, sxy = 0.0f;
    #pragma unroll
    for (int j = 0; j < 4; ++j) { sx += lhs[j] * lhs[j]; sy += rh[j] * rh[j]; sxy += lhs[j] * rh[j]; }
    const float x2  = wave_sum(sx);
    const float y2  = wave_sum(sy);
    const float xy  = wave_sum(sxy);
    const float ka  = 1.0f + 2.0f * c * xy + c * y2;
    const float kb  = 1.0f - c * x2;
    const float den = fmaxf(1.0f + 2.0f * c * xy + c * c * x2 * y2, MIN_NORM);
    float res[4];
    #pragma unroll
    for (int j = 0; j < 4; ++j) res[j] = (ka * lhs[j] + kb * rh[j]) / den;

    // project(res, c)
    s = 0.0f;
    #pragma unroll
    for (int j = 0; j < 4; ++j) s += res[j] * res[j];
    nrm = fmaxf(sqrtf(wave_sum(s)), MIN_NORM);
    if (nrm > maxnorm) {
        const float sc = maxnorm / nrm;
        #pragma unroll
        for (int j = 0; j < 4; ++j) res[j] *= sc;
    }

    // hyp_distance(res, tail, c)^2
    float sv = 0.0f, sxv = 0.0f, sxx = 0.0f;
    #pragma unroll
    for (int j = 0; j < 4; ++j) { sv += tl[j] * tl[j]; sxv += res[j] * tl[j]; sxx += res[j] * res[j]; }
    const float vnorm = fmaxf(sqrtf(wave_sum(sv)), MIN_NORM);
    const float xv    = wave_sum(sxv) / vnorm;
    const float rx2   = wave_sum(sxx);
    const float gamma = tanhf(sqrt_c * vnorm) / vnorm;
    const float c1 = 1.0f - 2.0f * c * gamma * xv + c * gamma * gamma;
    const float c2 = 1.0f - c * rx2;
    const float num = sqrtf(fmaxf(c1 * c1 * rx2 + c2 * c2 * gamma * gamma
                                  - 2.0f * c1 * c2 * gamma * xv, 0.0f));
    const float dden = fmaxf(1.0f - 2.0f * c * gamma * xv
                             + c * c * gamma * gamma * rx2, MIN_NORM);
    float arg = sqrt_c * num / dden;
    arg = fminf(fmaxf(arg, -1.0f + 1e-5f), 1.0f - 1e-5f);
    const float ath  = 0.5f * (log1pf(arg) - log1pf(-arg));
    const float dist = 2.0f * ath / sqrt_c;
    const float dist2 = dist * dist;

    // outputs
    float* out_pred = out;
    float* out_head = out + (size_t)NQ;
    float* out_rel  = out + (size_t)NQ + (size_t)NQ * D;
    float* out_tail = out + (size_t)NQ + (size_t)NQ * D + (size_t)NQ * 2 * D;

    if (lane == 0) {
        out_pred[q] = bias_head[h] + bias_tail[t] + dist2;
    }
    *(float4*)(out_head + (size_t)q * D     + e4) = head;
    *(float4*)(out_rel  + (size_t)q * 2 * D     + e4) = rel0;
    *(float4*)(out_rel  + (size_t)q * 2 * D + D + e4) = rel1;
    *(float4*)(out_tail + (size_t)q * D     + e4) = tail;
}

extern "C" void kernel_launch(void* const* d_in, const int* in_sizes, int n_in,
                              void* d_out, int out_size, void* d_ws, size_t ws_size,
                              hipStream_t stream) {
    const int*   queries     = (const int*)  d_in[0];
    const float* entity_emb  = (const float*)d_in[1];
    const float* rel_emb     = (const float*)d_in[2];
    const float* bias_head   = (const float*)d_in[3];
    const float* bias_tail   = (const float*)d_in[4];
    const float* c_arr       = (const float*)d_in[5];
    const float* att_rel_emb = (const float*)d_in[6];
    const float* context_emb = (const float*)d_in[7];
    float* out = (float*)d_out;

    const int queries_per_block = 4;                 // 4 waves of 64
    const int grid = (NQ + queries_per_block - 1) / queries_per_block;
    atth_kernel<<<grid, 256, 0, stream>>>(queries, entity_emb, rel_emb,
                                          bias_head, bias_tail, c_arr,
                                          att_rel_emb, context_emb, out);
}

// Round 2
// 367.023 us; speedup vs baseline: 1.0285x; 1.0285x over previous
//
#include <hip/hip_runtime.h>
#include <math.h>

#define MIN_NORM 1e-15f
#define BALL_EPS 0.004f

constexpr int D  = 256;
constexpr int NQ = 200000;
constexpr float SCALE = 0.0625f;   // 1/sqrt(256)

__device__ __forceinline__ float wave_sum(float v) {
    #pragma unroll
    for (int off = 32; off > 0; off >>= 1) v += __shfl_xor(v, off, 64);
    return v;
}

__device__ __forceinline__ void nt_store4(float* p, float4 v) {
    __builtin_nontemporal_store(v.x, p + 0);
    __builtin_nontemporal_store(v.y, p + 1);
    __builtin_nontemporal_store(v.z, p + 2);
    __builtin_nontemporal_store(v.w, p + 3);
}

__global__ __launch_bounds__(256) void atth_kernel(
    const int*   __restrict__ queries,
    const float* __restrict__ entity_emb,
    const float* __restrict__ rel_emb,
    const float* __restrict__ bias_head,
    const float* __restrict__ bias_tail,
    const float* __restrict__ c_arr,
    const float* __restrict__ att_rel_emb,
    const float* __restrict__ context_emb,
    float*       __restrict__ out)
{
    const int wave = threadIdx.x >> 6;
    const int lane = threadIdx.x & 63;
    const int q = blockIdx.x * 4 + wave;
    if (q >= NQ) return;

    const int h = queries[q * 3 + 0];
    const int r = queries[q * 3 + 1];
    const int t = queries[q * 3 + 2];

    // c_q = softplus(c[r])
    const float craw = c_arr[r];
    const float c = (craw > 20.0f) ? craw : log1pf(expf(craw));
    const float sqrt_c = sqrtf(c);

    const int e4 = lane * 4;

    const float4 head = *(const float4*)(entity_emb  + (size_t)h * D       + e4);
    const float4 tail = *(const float4*)(entity_emb  + (size_t)t * D       + e4);
    const float4 rel0 = *(const float4*)(rel_emb     + (size_t)r * 2 * D       + e4);
    const float4 rel1 = *(const float4*)(rel_emb     + (size_t)r * 2 * D + D   + e4);
    const float4 rotm = *(const float4*)(att_rel_emb + (size_t)r * 2 * D       + e4);
    const float4 refm = *(const float4*)(att_rel_emb + (size_t)r * 2 * D + D   + e4);
    const float4 ctx  = *(const float4*)(context_emb + (size_t)r * D       + e4);

    const float hd[4]  = {head.x, head.y, head.z, head.w};
    const float tl[4]  = {tail.x, tail.y, tail.z, tail.w};
    const float rm[4]  = {rotm.x, rotm.y, rotm.z, rotm.w};
    const float fm[4]  = {refm.x, refm.y, refm.z, refm.w};
    const float cx[4]  = {ctx.x,  ctx.y,  ctx.z,  ctx.w};
    const float rl[4]  = {rel0.x, rel0.y, rel0.z, rel0.w};

    // Givens rotation (rot_mat) and reflection (ref_mat) on the 2 local pairs
    float rq[4], fq[4];
    #pragma unroll
    for (int p = 0; p < 2; ++p) {
        const int i0 = 2 * p, i1 = 2 * p + 1;
        // rotation
        float g0 = rm[i0], g1 = rm[i1];
        float n  = fmaxf(sqrtf(g0 * g0 + g1 * g1), MIN_NORM);
        g0 /= n; g1 /= n;
        rq[i0] = g0 * hd[i0] - g1 * hd[i1];
        rq[i1] = g0 * hd[i1] + g1 * hd[i0];
        // reflection
        float e0 = fm[i0], e1 = fm[i1];
        float m  = fmaxf(sqrtf(e0 * e0 + e1 * e1), MIN_NORM);
        e0 /= m; e1 /= m;
        fq[i0] = e0 * hd[i0] + e1 * hd[i1];
        fq[i1] = e1 * hd[i0] - e0 * hd[i1];
    }

    // attention over {ref_q, rot_q}
    float sref = 0.0f, srot = 0.0f;
    #pragma unroll
    for (int j = 0; j < 4; ++j) { sref += cx[j] * fq[j]; srot += cx[j] * rq[j]; }
    sref = wave_sum(sref) * SCALE;
    srot = wave_sum(srot) * SCALE;
    const float mx = fmaxf(sref, srot);
    const float eref = expf(sref - mx), erot = expf(srot - mx);
    const float inv_se = 1.0f / (eref + erot);
    const float wref = eref * inv_se, wrot = erot * inv_se;

    float att[4];
    #pragma unroll
    for (int j = 0; j < 4; ++j) att[j] = wref * fq[j] + wrot * rq[j];

    const float maxnorm = (1.0f - BALL_EPS) / sqrt_c;

    // lhs = expmap0(att_q, c) with project
    float s = 0.0f;
    #pragma unroll
    for (int j = 0; j < 4; ++j) s += att[j] * att[j];
    float un = fmaxf(sqrtf(wave_sum(s)), MIN_NORM);
    float fac = tanhf(sqrt_c * un) / (sqrt_c * un);
    float lhs[4];
    #pragma unroll
    for (int j = 0; j < 4; ++j) lhs[j] = fac * att[j];
    s = 0.0f;
    #pragma unroll
    for (int j = 0; j < 4; ++j) s += lhs[j] * lhs[j];
    float nrm = fmaxf(sqrtf(wave_sum(s)), MIN_NORM);
    if (nrm > maxnorm) {
        const float sc = maxnorm / nrm;
        #pragma unroll
        for (int j = 0; j < 4; ++j) lhs[j] *= sc;
    }

    // rel = expmap0(rel_emb[r][:D], c) with project
    s = 0.0f;
    #pragma unroll
    for (int j = 0; j < 4; ++j) s += rl[j] * rl[j];
    un = fmaxf(sqrtf(wave_sum(s)), MIN_NORM);
    fac = tanhf(sqrt_c * un) / (sqrt_c * un);
    float rh[4];
    #pragma unroll
    for (int j = 0; j < 4; ++j) rh[j] = fac * rl[j];
    s = 0.0f;
    #pragma unroll
    for (int j = 0; j < 4; ++j) s += rh[j] * rh[j];
    nrm = fmaxf(sqrtf(wave_sum(s)), MIN_NORM);
    if (nrm > maxnorm) {
        const float sc = maxnorm / nrm;
        #pragma unroll
        for (int j = 0; j < 4; ++j) rh[j] *= sc;
    }

    // mobius_add(lhs, rh, c)
    float sx = 0.0f, sy = 0.0f, sxy = 0.0f;
    #pragma unroll
    for (int j = 0; j < 4; ++j) { sx += lhs[j] * lhs[j]; sy += rh[j] * rh[j]; sxy += lhs[j] * rh[j]; }
    const float x2  = wave_sum(sx);
    const float y2  = wave_sum(sy);
    const float xy  = wave_sum(sxy);
    const float ka  = 1.0f + 2.0f * c * xy + c * y2;
    const float kb  = 1.0f - c * x2;
    const float den = fmaxf(1.0f + 2.0f * c * xy + c * c * x2 * y2, MIN_NORM);
    float res[4];
    #pragma unroll
    for (int j = 0; j < 4; ++j) res[j] = (ka * lhs[j] + kb * rh[j]) / den;

    // project(res, c)
    s = 0.0f;
    #pragma unroll
    for (int j = 0; j < 4; ++j) s += res[j] * res[j];
    nrm = fmaxf(sqrtf(wave_sum(s)), MIN_NORM);
    if (nrm > maxnorm) {
        const float sc = maxnorm / nrm;
        #pragma unroll
        for (int j = 0; j < 4; ++j) res[j] *= sc;
    }

    // hyp_distance(res, tail, c)^2
    float sv = 0.0f, sxv = 0.0f, sxx = 0.0f;
    #pragma unroll
    for (int j = 0; j < 4; ++j) { sv += tl[j] * tl[j]; sxv += res[j] * tl[j]; sxx += res[j] * res[j]; }
    const float vnorm = fmaxf(sqrtf(wave_sum(sv)), MIN_NORM);
    const float xv    = wave_sum(sxv) / vnorm;
    const float rx2   = wave_sum(sxx);
    const float gamma = tanhf(sqrt_c * vnorm) / vnorm;
    const float c1 = 1.0f - 2.0f * c * gamma * xv + c * gamma * gamma;
    const float c2 = 1.0f - c * rx2;
    const float num = sqrtf(fmaxf(c1 * c1 * rx2 + c2 * c2 * gamma * gamma
                                  - 2.0f * c1 * c2 * gamma * xv, 0.0f));
    const float dden = fmaxf(1.0f - 2.0f * c * gamma * xv
                             + c * c * gamma * gamma * rx2, MIN_NORM);
    float arg = sqrt_c * num / dden;
    arg = fminf(fmaxf(arg, -1.0f + 1e-5f), 1.0f - 1e-5f);
    const float ath  = 0.5f * (log1pf(arg) - log1pf(-arg));
    const float dist = 2.0f * ath / sqrt_c;
    const float dist2 = dist * dist;

    // outputs (all streaming -> non-temporal, no write-allocate)
    float* out_pred = out;
    float* out_head = out + (size_t)NQ;
    float* out_rel  = out + (size_t)NQ + (size_t)NQ * D;
    float* out_tail = out + (size_t)NQ + (size_t)NQ * D + (size_t)NQ * 2 * D;

    if (lane == 0) {
        __builtin_nontemporal_store(bias_head[h] + bias_tail[t] + dist2, out_pred + q);
    }
    nt_store4(out_head + (size_t)q * D     + e4, head);
    nt_store4(out_rel  + (size_t)q * 2 * D     + e4, rel0);
    nt_store4(out_rel  + (size_t)q * 2 * D + D + e4, rel1);
    nt_store4(out_tail + (size_t)q * D     + e4, tail);
}

extern "C" void kernel_launch(void* const* d_in, const int* in_sizes, int n_in,
                              void* d_out, int out_size, void* d_ws, size_t ws_size,
                              hipStream_t stream) {
    const int*   queries     = (const int*)  d_in[0];
    const float* entity_emb  = (const float*)d_in[1];
    const float* rel_emb     = (const float*)d_in[2];
    const float* bias_head   = (const float*)d_in[3];
    const float* bias_tail   = (const float*)d_in[4];
    const float* c_arr       = (const float*)d_in[5];
    const float* att_rel_emb = (const float*)d_in[6];
    const float* context_emb = (const float*)d_in[7];
    float* out = (float*)d_out;

    const int queries_per_block = 4;                 // 4 waves of 64
    const int grid = (NQ + queries_per_block - 1) / queries_per_block;
    atth_kernel<<<grid, 256, 0, stream>>>(queries, entity_emb, rel_emb,
                                          bias_head, bias_tail, c_arr,
                                          att_rel_emb, context_emb, out);
}

// Round 4
// 350.969 us; speedup vs baseline: 1.0755x; 1.0457x over previous
//
#include <hip/hip_runtime.h>
#include <math.h>

#define MIN_NORM 1e-15f
#define BALL_EPS 0.004f

constexpr int D  = 256;
constexpr int NQ = 200000;
constexpr float SCALE = 0.0625f;   // 1/sqrt(256)

__device__ __forceinline__ void nt_store4(float* p, float4 v) {
    __builtin_nontemporal_store(v.x, p + 0);
    __builtin_nontemporal_store(v.y, p + 1);
    __builtin_nontemporal_store(v.z, p + 2);
    __builtin_nontemporal_store(v.w, p + 3);
}

// 4 batched reductions over each 32-lane half (xor offsets < 32 keep halves independent)
__device__ __forceinline__ void half_sum4(float& a, float& b, float& c, float& d) {
    #pragma unroll
    for (int off = 16; off > 0; off >>= 1) {
        a += __shfl_xor(a, off, 64);
        b += __shfl_xor(b, off, 64);
        c += __shfl_xor(c, off, 64);
        d += __shfl_xor(d, off, 64);
    }
}

__device__ __forceinline__ void unpack8(float4 a, float4 b, float* d) {
    d[0] = a.x; d[1] = a.y; d[2] = a.z; d[3] = a.w;
    d[4] = b.x; d[5] = b.y; d[6] = b.z; d[7] = b.w;
}

__device__ __forceinline__ float tanh_pos(float x) {   // x >= 0
    const float e = __expf(-2.0f * x);
    return (1.0f - e) / (1.0f + e);
}

__global__ __launch_bounds__(256) void atth_kernel(
    const int*   __restrict__ queries,
    const float* __restrict__ entity_emb,
    const float* __restrict__ rel_emb,
    const float* __restrict__ bias_head,
    const float* __restrict__ bias_tail,
    const float* __restrict__ c_arr,
    const float* __restrict__ att_rel_emb,
    const float* __restrict__ context_emb,
    float*       __restrict__ out)
{
    const int lane = threadIdx.x & 63;
    const int hl   = lane & 31;                       // lane within 32-half
    const int qid  = blockIdx.x * 8 + (threadIdx.x >> 5);
    if (qid >= NQ) return;

    const int h = queries[qid * 3 + 0];
    const int r = queries[qid * 3 + 1];
    const int t = queries[qid * 3 + 2];

    // c_q = softplus(c[r])   (stable form)
    const float craw   = c_arr[r];
    const float cq     = fmaxf(craw, 0.0f) + log1pf(__expf(-fabsf(craw)));
    const float sqrt_c = sqrtf(cq);

    const int e8 = hl * 8;

    const float* eh = entity_emb  + (size_t)h * D     + e8;
    const float* et = entity_emb  + (size_t)t * D     + e8;
    const float* rr = rel_emb     + (size_t)r * 2 * D + e8;
    const float* am = att_rel_emb + (size_t)r * 2 * D + e8;
    const float* cb = context_emb + (size_t)r * D     + e8;

    const float4 h0 = *(const float4*)(eh);     const float4 h1 = *(const float4*)(eh + 4);
    const float4 t0 = *(const float4*)(et);     const float4 t1 = *(const float4*)(et + 4);
    const float4 r0 = *(const float4*)(rr);     const float4 r1 = *(const float4*)(rr + 4);
    const float4 r2 = *(const float4*)(rr + D); const float4 r3 = *(const float4*)(rr + D + 4);
    const float4 m0 = *(const float4*)(am);     const float4 m1 = *(const float4*)(am + 4);
    const float4 f0 = *(const float4*)(am + D); const float4 f1 = *(const float4*)(am + D + 4);
    const float4 ct0 = *(const float4*)(cb);    const float4 ct1 = *(const float4*)(cb + 4);

    // --- streaming copies to output, issued early so they overlap compute ---
    float* out_pred = out;
    float* out_head = out + (size_t)NQ;
    float* out_rel  = out + (size_t)NQ + (size_t)NQ * D;
    float* out_tail = out + (size_t)NQ + (size_t)NQ * D + (size_t)NQ * 2 * D;

    nt_store4(out_head + (size_t)qid * D         + e8,     h0);
    nt_store4(out_head + (size_t)qid * D         + e8 + 4, h1);
    nt_store4(out_rel  + (size_t)qid * 2 * D     + e8,     r0);
    nt_store4(out_rel  + (size_t)qid * 2 * D     + e8 + 4, r1);
    nt_store4(out_rel  + (size_t)qid * 2 * D + D + e8,     r2);
    nt_store4(out_rel  + (size_t)qid * 2 * D + D + e8 + 4, r3);
    nt_store4(out_tail + (size_t)qid * D         + e8,     t0);
    nt_store4(out_tail + (size_t)qid * D         + e8 + 4, t1);

    float hd[8], tl[8], rl[8], rm[8], fm[8], cx[8];
    unpack8(h0, h1, hd);
    unpack8(t0, t1, tl);
    unpack8(r0, r1, rl);
    unpack8(m0, m1, rm);
    unpack8(f0, f1, fm);
    unpack8(ct0, ct1, cx);

    // Givens rotation + reflection on 4 local pairs (rsqrt instead of div+sqrt)
    float rq[8], fq[8];
    #pragma unroll
    for (int p = 0; p < 4; ++p) {
        const int i0 = 2 * p, i1 = 2 * p + 1;
        float s   = rm[i0] * rm[i0] + rm[i1] * rm[i1];
        float inv = rsqrtf(fmaxf(s, 1e-30f));          // == 1/max(sqrt(s),1e-15)
        const float g0 = rm[i0] * inv, g1 = rm[i1] * inv;
        rq[i0] = g0 * hd[i0] - g1 * hd[i1];
        rq[i1] = g0 * hd[i1] + g1 * hd[i0];
        s   = fm[i0] * fm[i0] + fm[i1] * fm[i1];
        inv = rsqrtf(fmaxf(s, 1e-30f));
        const float e0 = fm[i0] * inv, e1 = fm[i1] * inv;
        fq[i0] = e0 * hd[i0] + e1 * hd[i1];
        fq[i1] = e1 * hd[i0] - e0 * hd[i1];
    }

    // ---- reduction stage 1: sref, srot, ||rl||^2, ||tail||^2 ----
    float sref = 0.0f, srot = 0.0f, url2 = 0.0f, sv = 0.0f;
    #pragma unroll
    for (int j = 0; j < 8; ++j) {
        sref += cx[j] * fq[j];
        srot += cx[j] * rq[j];
        url2 += rl[j] * rl[j];
        sv   += tl[j] * tl[j];
    }
    half_sum4(sref, srot, url2, sv);
    sref *= SCALE; srot *= SCALE;

    // softmax over the 2 candidates
    const float mx   = fmaxf(sref, srot);
    const float eref = __expf(sref - mx), erot = __expf(srot - mx);
    const float inv_se = 1.0f / (eref + erot);
    const float wref = eref * inv_se, wrot = erot * inv_se;

    float att[8];
    #pragma unroll
    for (int j = 0; j < 8; ++j) att[j] = wref * fq[j] + wrot * rq[j];

    // ---- reduction stage 2: ||att||^2, att.rl, att.tail, rl.tail ----
    float u2 = 0.0f, adr = 0.0f, atl = 0.0f, rtl = 0.0f;
    #pragma unroll
    for (int j = 0; j < 8; ++j) {
        u2  += att[j] * att[j];
        adr += att[j] * rl[j];
        atl += att[j] * tl[j];
        rtl += rl[j]  * tl[j];
    }
    half_sum4(u2, adr, atl, rtl);

    // ---- all remaining math is scalar (uniform within the half-wave) ----
    const float maxnorm = (1.0f - BALL_EPS) / sqrt_c;

    // lhs = project(expmap0(att, c)): lhs = sA * att
    const float u    = fmaxf(sqrtf(u2), MIN_NORM);
    const float facA = tanh_pos(sqrt_c * u) / (sqrt_c * u);
    const float nA   = facA * u;                          // ||expmap0(att)||
    const float sA   = facA * ((nA > maxnorm) ? maxnorm / nA : 1.0f);
    const float x2   = sA * sA * u2;

    // rh = project(expmap0(rl, c)): rh = sB * rl
    const float url  = fmaxf(sqrtf(url2), MIN_NORM);
    const float facB = tanh_pos(sqrt_c * url) / (sqrt_c * url);
    const float nB   = facB * url;
    const float sB   = facB * ((nB > maxnorm) ? maxnorm / nB : 1.0f);
    const float y2   = sB * sB * url2;

    const float xy = sA * sB * adr;

    // mobius_add(lhs, rh, c): res = pA*att + pB*rl
    const float ka  = 1.0f + 2.0f * cq * xy + cq * y2;
    const float kb  = 1.0f - cq * x2;
    const float den = fmaxf(1.0f + 2.0f * cq * xy + cq * cq * x2 * y2, MIN_NORM);
    const float pA  = ka * sA / den;
    const float pB  = kb * sB / den;

    // project(res, c) analytically
    const float rn2 = pA * pA * u2 + 2.0f * pA * pB * adr + pB * pB * url2;
    const float nrm = fmaxf(sqrtf(rn2), MIN_NORM);
    const float pr  = (nrm > maxnorm) ? maxnorm / nrm : 1.0f;
    const float rx2 = rn2 * pr * pr;

    // hyp_distance(res, tail, c)^2
    const float vnorm = fmaxf(sqrtf(sv), MIN_NORM);
    const float sxv   = (pA * atl + pB * rtl) * pr;       // res . tail
    const float xv    = sxv / vnorm;
    const float gamma = tanh_pos(sqrt_c * vnorm) / vnorm;
    const float k1 = 1.0f - 2.0f * cq * gamma * xv + cq * gamma * gamma;
    const float k2 = 1.0f - cq * rx2;
    const float num = sqrtf(fmaxf(k1 * k1 * rx2 + k2 * k2 * gamma * gamma
                                  - 2.0f * k1 * k2 * gamma * xv, 0.0f));
    const float dden = fmaxf(1.0f - 2.0f * cq * gamma * xv
                             + cq * cq * gamma * gamma * rx2, MIN_NORM);
    float arg = sqrt_c * num / dden;
    arg = fminf(fmaxf(arg, -1.0f + 1e-5f), 1.0f - 1e-5f);
    const float ath  = 0.5f * __logf((1.0f + arg) / (1.0f - arg));
    const float dist = 2.0f * ath / sqrt_c;
    const float dist2 = dist * dist;

    if (hl == 0) {
        __builtin_nontemporal_store(bias_head[h] + bias_tail[t] + dist2, out_pred + qid);
    }
}

extern "C" void kernel_launch(void* const* d_in, const int* in_sizes, int n_in,
                              void* d_out, int out_size, void* d_ws, size_t ws_size,
                              hipStream_t stream) {
    const int*   queries     = (const int*)  d_in[0];
    const float* entity_emb  = (const float*)d_in[1];
    const float* rel_emb     = (const float*)d_in[2];
    const float* bias_head   = (const float*)d_in[3];
    const float* bias_tail   = (const float*)d_in[4];
    const float* c_arr       = (const float*)d_in[5];
    const float* att_rel_emb = (const float*)d_in[6];
    const float* context_emb = (const float*)d_in[7];
    float* out = (float*)d_out;

    const int queries_per_block = 8;                 // 8 half-waves of 32
    const int grid = (NQ + queries_per_block - 1) / queries_per_block;
    atth_kernel<<<grid, 256, 0, stream>>>(queries, entity_emb, rel_emb,
                                          bias_head, bias_tail, c_arr,
                                          att_rel_emb, context_emb, out);
}